// Round 3
// baseline (566.759 us; speedup 1.0000x reference)
//
#include <hip/hip_runtime.h>

// ---------------------------------------------------------------------------
// EdgeNetwork: out[e] = tanh(relu(cat(h[dst[e]], h[src[e]], dR[e]) @ W1 + b1) @ W2 + b2)
// E=640000, F=128, MID=192, OUT=128.  bf16 MFMA (16x16x32), fp32 accumulate.
// v4: effective-HBM-bound diagnosis (v1/v2/v3 all ~3.0-3.1 TB/s regardless of
// structure) -> minimize HBM bytes:
//   - DOUBLE-TRANSPOSED dataflow: hid^T = W1^T·A^T, out^T = W2^T·hid^T.
//     Same packed weights, same LDS patterns; C-fragment now holds 4
//     CONSECUTIVE out columns per lane -> float4 epilogues.
//   - Full-line nontemporal float4 stores: wave w owns the contiguous 128B
//     line n in [32w, 32w+32) of every row; mi=0/1 stores fill both 64B
//     halves back-to-back (v2's NT half-line 1.44x write amplification gone).
//   - NT stores don't allocate in L2/L3 -> 25.6MB bf16 h table stays
//     L3-resident -> gather re-fetch eliminated.
//   - epilogue1: float4 b1/wdr loads, packed ds_write_b64 (12 vs 48 writes),
//     4 dR shuffles (vs 16).
//   - W2 register-persistent; W1 per-tile from L2 (VGPR headroom).
//   - v3 persistent-block double-buffer pipeline skeleton kept.
// ---------------------------------------------------------------------------

#define F_IN   128
#define MID    192
#define OUT_N  128
#define K1     256          // 2*F (dR column handled as rank-1 epilogue)
#define M_TILE 64           // edges per tile
#define H_STRIDE 200        // bf16 elements; 400 B rows
#define NBLK   512          // persistent grid: 2 blocks/CU

typedef __attribute__((ext_vector_type(8))) short bf16x8;            // 8 bf16 = 4 VGPRs
typedef __attribute__((ext_vector_type(8))) unsigned short u16x8;
typedef __attribute__((ext_vector_type(4))) float f32x4;
typedef __attribute__((ext_vector_type(2))) unsigned int u32x2;

__device__ __forceinline__ unsigned short f2bf(float f) {
    unsigned u = __builtin_bit_cast(unsigned, f);
    u = (u + 0x7FFFu + ((u >> 16) & 1u)) >> 16;   // round-to-nearest-even
    return (unsigned short)u;
}

// Pack W1 (rows 0..255) and W2 into bf16, fragment-major:
//   p[(ktile*N + n)*32 + kin], k = ktile*32 + kin.
// Serves as A-operand (W^T) fragments: lane(q,l15) reads 8 shorts at
// ((kt*N + mt*16+l15)*32 + q*8) = W[kt*32+q*8+j][mt*16+l15] = W^T[n][k]. 
__global__ void pack_weights(const float* __restrict__ W1,
                             const float* __restrict__ W2,
                             unsigned short* __restrict__ p1,
                             unsigned short* __restrict__ p2,
                             float* __restrict__ wdr) {
    int i = blockIdx.x * 256 + threadIdx.x;
    if (i < K1 * MID) {              // 49152
        int kin = i & 31;
        int rest = i >> 5;
        int n = rest % MID;
        int kt = rest / MID;
        p1[i] = f2bf(W1[(kt * 32 + kin) * MID + n]);
    }
    int j = i - K1 * MID;
    if (j >= 0 && j < MID * OUT_N) { // 24576
        int kin = j & 31;
        int rest = j >> 5;
        int n = rest & 127;
        int kt = rest >> 7;
        p2[j] = f2bf(W2[(kt * 32 + kin) * OUT_N + n]);
    }
    if (i < MID) wdr[i] = W1[256 * MID + i];
}

// h (fp32) -> hb (bf16), 8 elements/thread
__global__ void hconv(const float* __restrict__ h,
                      unsigned short* __restrict__ hb, int n8) {
    int i = blockIdx.x * 256 + threadIdx.x;
    if (i >= n8) return;
    const float4* hp = (const float4*)h;
    float4 v0 = hp[2 * i];
    float4 v1 = hp[2 * i + 1];
    u16x8 o;
    o[0] = f2bf(v0.x); o[1] = f2bf(v0.y); o[2] = f2bf(v0.z); o[3] = f2bf(v0.w);
    o[4] = f2bf(v1.x); o[5] = f2bf(v1.y); o[6] = f2bf(v1.z); o[7] = f2bf(v1.w);
    *((u16x8*)hb + i) = o;
}

#define SBAR()  do { __builtin_amdgcn_sched_barrier(0); \
                     __builtin_amdgcn_s_barrier();      \
                     __builtin_amdgcn_sched_barrier(0); } while (0)

__global__ __launch_bounds__(256, 2)
void edge_mlp_kernel(const unsigned short* __restrict__ hb,
                     const float* __restrict__ dR,
                     const int*   __restrict__ src_idx,
                     const int*   __restrict__ dst_idx,
                     const float* __restrict__ b1,
                     const float* __restrict__ b2,
                     const unsigned short* __restrict__ p1,
                     const unsigned short* __restrict__ p2,
                     const float* __restrict__ wdr,
                     float* __restrict__ out,
                     int NT) {
    // A tile: 64 edges x 256 bf16 (dst row | src row), linear 512 B/edge.
    // 16B chunk c of edge e holds GLOBAL chunk c ^ (e&7) (source-side swizzle:
    // global_load_lds dest is wave-uniform base + lane*16, so LDS stays linear).
    __shared__ __align__(16) unsigned short sA[2][M_TILE * 256];   // 65536 B -> 2 blocks/CU

    const int tid  = threadIdx.x;
    const int lane = tid & 63;
    const int w    = tid >> 6;          // wave 0..3
    const int l15  = lane & 15;
    const int q    = lane >> 4;

    // staging geometry: g selects {e dst, e src, e+1 dst, e+1 src}; c = 16B chunk
    const int g    = lane >> 4;
    const int c    = lane & 15;
    const int part = g & 1;
    const int* __restrict__ ip = part ? src_idx : dst_idx;
    const int eb   = w * 16 + (g >> 1);

    // ---- persistent W2^T A-operand fragments: wave w owns out-rows mt={2w,2w+1} ----
    bf16x8 w2f[6][2];                   // 48 VGPR
#pragma unroll
    for (int kt = 0; kt < 6; ++kt)
#pragma unroll
        for (int mi = 0; mi < 2; ++mi) {
            const int nb = (2 * w + mi) * 16 + l15;
            w2f[kt][mi] = *(const bf16x8*)(&p2[((kt * OUT_N + nb) << 5) + (q << 3)]);
        }

    const int t0 = blockIdx.x;
    if (t0 >= NT) return;

    // ---- prologue: stage tile t0 into buf 0; prefetch idx/dR of t0+NBLK ----
    int idxc[8];                        // indices for the NEXT tile to stage
    {
        const int base = t0 * M_TILE + eb;
#pragma unroll
        for (int i = 0; i < 8; ++i) idxc[i] = ip[base + 2 * i];
#pragma unroll
        for (int i = 0; i < 8; ++i) {
            const int el = eb + 2 * i;
            const unsigned short* gp =
                hb + ((size_t)idxc[i] << 7) + ((c ^ (el & 7)) << 3);
            unsigned short* lp = &sA[0][(w * 16 + 2 * i) * 256];
            __builtin_amdgcn_global_load_lds(
                (const __attribute__((address_space(1))) void*)gp,
                (__attribute__((address_space(3))) void*)lp, 16, 0, 0);
        }
    }
    int t1 = t0 + NBLK; if (t1 > NT - 1) t1 = NT - 1;   // clamped (always valid)
    {
        const int base = t1 * M_TILE + eb;
#pragma unroll
        for (int i = 0; i < 8; ++i) idxc[i] = ip[base + 2 * i];
    }
    float dr_now = dR[t0 * M_TILE + lane];
    float dr_nxt = dR[t1 * M_TILE + lane];

    int cur = 0;
    for (int t = t0; t < NT; t += NBLK, cur ^= 1) {
        // ---- 1. issue gathers for next tile (idx-reg vmcnt dep retires stage(t)) ----
#pragma unroll
        for (int i = 0; i < 8; ++i) {
            const int el = eb + 2 * i;
            const unsigned short* gp =
                hb + ((size_t)idxc[i] << 7) + ((c ^ (el & 7)) << 3);
            unsigned short* lp = &sA[cur ^ 1][(w * 16 + 2 * i) * 256];
            __builtin_amdgcn_global_load_lds(
                (const __attribute__((address_space(1))) void*)gp,
                (__attribute__((address_space(3))) void*)lp, 16, 0, 0);
        }
        // ---- 2. prefetch idx for t+2*NBLK ----
        {
            int t2 = t + 2 * NBLK; if (t2 > NT - 1) t2 = NT - 1;
            const int base = t2 * M_TILE + eb;
#pragma unroll
            for (int i = 0; i < 8; ++i) idxc[i] = ip[base + 2 * i];
        }
        // ---- 3. B1: stage(t) visible to all waves ----
        SBAR();

        // ---- 4. layer 1: hid^T = W1^T (A) x A^T (B).  acc1[mi][et]:
        //         C col = edge (l15), C row = n_local (q*4+r).  96 MFMA/wave ----
        const unsigned short* sAc = &sA[cur][0];
        f32x4 acc1[3][4] = {};
        for (int kt = 0; kt < 8; ++kt) {
            bf16x8 bfr[4];
#pragma unroll
            for (int et = 0; et < 4; ++et) {
                const int r = et * 16 + l15;
                bfr[et] = *(const bf16x8*)(&sAc[r * 256 + (((kt * 4 + q) ^ (r & 7)) << 3)]);
            }
            bf16x8 w1a[3];
#pragma unroll
            for (int mi = 0; mi < 3; ++mi) {
                const int nb = (3 * w + mi) * 16 + l15;
                w1a[mi] = *(const bf16x8*)(&p1[((kt * MID + nb) << 5) + (q << 3)]);
            }
#pragma unroll
            for (int mi = 0; mi < 3; ++mi)
#pragma unroll
                for (int et = 0; et < 4; ++et)
                    acc1[mi][et] = __builtin_amdgcn_mfma_f32_16x16x32_bf16(
                        w1a[mi], bfr[et], acc1[mi][et], 0, 0, 0);
        }
        // ---- B2: all waves done reading A before hid overwrites it ----
        SBAR();

        // dR for the 4 edge columns this lane owns (e = et*16 + l15)
        float drl[4];
#pragma unroll
        for (int et = 0; et < 4; ++et) drl[et] = __shfl(dr_now, et * 16 + l15);

        // ---- epilogue 1 -> hid (bf16) in LDS [e][n], aliasing sA[cur].
        //      lane holds n = n0..n0+3 (consecutive) for each (mi,et): b64 write ----
        unsigned short* sH = &sA[cur][0];
#pragma unroll
        for (int mi = 0; mi < 3; ++mi) {
            const int n0 = (3 * w + mi) * 16 + q * 4;
            const f32x4 bb = *(const f32x4*)(b1 + n0);
            const f32x4 wd = *(const f32x4*)(wdr + n0);
#pragma unroll
            for (int et = 0; et < 4; ++et) {
                const int e = et * 16 + l15;
                unsigned pk0, pk1;
                {
                    float v0 = fmaxf(acc1[mi][et][0] + bb[0] + drl[et] * wd[0], 0.0f);
                    float v1 = fmaxf(acc1[mi][et][1] + bb[1] + drl[et] * wd[1], 0.0f);
                    float v2 = fmaxf(acc1[mi][et][2] + bb[2] + drl[et] * wd[2], 0.0f);
                    float v3 = fmaxf(acc1[mi][et][3] + bb[3] + drl[et] * wd[3], 0.0f);
                    pk0 = (unsigned)f2bf(v0) | ((unsigned)f2bf(v1) << 16);
                    pk1 = (unsigned)f2bf(v2) | ((unsigned)f2bf(v3) << 16);
                }
                u32x2 pk; pk[0] = pk0; pk[1] = pk1;
                *(u32x2*)(&sH[e * H_STRIDE + n0]) = pk;
            }
        }
        asm volatile("s_waitcnt lgkmcnt(0)" ::: "memory");
        // ---- B3: hid visible before layer-2 reads ----
        SBAR();

        // ---- layer 2: out^T = W2^T (A) x hid^T (B).  48 MFMA/wave ----
        f32x4 acc2[2][4] = {};
        for (int kt = 0; kt < 6; ++kt) {
            bf16x8 hfr[4];
#pragma unroll
            for (int et = 0; et < 4; ++et)
                hfr[et] = *(const bf16x8*)(&sH[(et * 16 + l15) * H_STRIDE + kt * 32 + q * 8]);
#pragma unroll
            for (int mi = 0; mi < 2; ++mi)
#pragma unroll
                for (int et = 0; et < 4; ++et)
                    acc2[mi][et] = __builtin_amdgcn_mfma_f32_16x16x32_bf16(
                        w2f[kt][mi], hfr[et], acc2[mi][et], 0, 0, 0);
        }
        // ---- B4: all waves done reading sH before next stage overwrites it ----
        SBAR();

        // ---- epilogue 2: tanh + full-line nontemporal float4 stores.
        //      lane (q,l15) stores out[e][n0..n0+3]; wave w owns the whole
        //      128B line n in [32w,32w+32) of each row; mi=0/1 back-to-back
        //      fill both 64B halves -> full-line NT writes, no L2/L3 pollution ----
        f32x4 bb2v[2];
#pragma unroll
        for (int mi = 0; mi < 2; ++mi)
            bb2v[mi] = *(const f32x4*)(b2 + (2 * w + mi) * 16 + q * 4);
#pragma unroll
        for (int et = 0; et < 4; ++et) {
            const size_t e = (size_t)(t * M_TILE + et * 16 + l15);
#pragma unroll
            for (int mi = 0; mi < 2; ++mi) {
                const int n0 = (2 * w + mi) * 16 + q * 4;
                f32x4 y;
#pragma unroll
                for (int r = 0; r < 4; ++r) {
                    float x = acc2[mi][et][r] + bb2v[mi][r];
                    x = fminf(fmaxf(x, -10.0f), 10.0f);
                    float tt = __expf(2.0f * x);          // tanh = (e^2x-1)/(e^2x+1)
                    y[r] = (tt - 1.0f) * __builtin_amdgcn_rcpf(tt + 1.0f);
                }
                __builtin_nontemporal_store(y, (f32x4*)(out + e * OUT_N + n0));
            }
        }

        // ---- roll dR pipeline ----
        dr_now = dr_nxt;
        {
            int t2 = t + 2 * NBLK; if (t2 > NT - 1) t2 = NT - 1;
            dr_nxt = dR[t2 * M_TILE + lane];
        }
    }
}

extern "C" void kernel_launch(void* const* d_in, const int* in_sizes, int n_in,
                              void* d_out, int out_size, void* d_ws, size_t ws_size,
                              hipStream_t stream) {
    const float* h   = (const float*)d_in[0];
    const float* dR  = (const float*)d_in[1];
    const int* src   = (const int*)d_in[2];
    const int* dst   = (const int*)d_in[3];
    const float* W1  = (const float*)d_in[4];
    const float* b1  = (const float*)d_in[5];
    const float* W2  = (const float*)d_in[6];
    const float* b2  = (const float*)d_in[7];
    float* out       = (float*)d_out;

    const int hn = in_sizes[0];   // n_nodes * 128 elements
    const int E  = in_sizes[1];
    const int NT = E / M_TILE;

    // workspace layout: hb (hn bf16) | p1 | p2 | wdr   (~25.75 MB total)
    unsigned short* hbuf = (unsigned short*)d_ws;
    unsigned short* p1   = hbuf + hn;
    unsigned short* p2   = p1 + K1 * MID;
    float* wdr           = (float*)(p2 + MID * OUT_N);

    hconv<<<(hn / 8 + 255) / 256, 256, 0, stream>>>(h, hbuf, hn / 8);
    pack_weights<<<(K1 * MID + MID * OUT_N + 255) / 256, 256, 0, stream>>>(W1, W2, p1, p2, wdr);

    const int grid = NT < NBLK ? NT : NBLK;
    edge_mlp_kernel<<<grid, 256, 0, stream>>>(hbuf, dR, src, dst, b1, b2, p1, p2, wdr, out, NT);
}

// Round 4
// 520.984 us; speedup vs baseline: 1.0879x; 1.0879x over previous
//
#include <hip/hip_runtime.h>

// ---------------------------------------------------------------------------
// EdgeNetwork: out[e] = tanh(relu(cat(h[dst[e]], h[src[e]], dR[e]) @ W1 + b1) @ W2 + b2)
// E=640000, F=128, MID=192, OUT=128.  bf16 MFMA (16x16x32), fp32 accumulate.
// v5: bytes-minimal combination of the per-version verified winners.
//   Evidence: effective HBM BW pinned at ~3.0 TB/s in v1-v4 regardless of
//   structure -> time = hbm_bytes / 3 TB/s.  Therefore:
//   - bf16 h table + global_load_lds gathers  (v2: FETCH 309->159 MB)
//   - PLAIN stores (v1: WRITE 320 MB = ideal; NT inflated 1.45x both times)
//   - transposed dataflow (v4): C-fragment holds 4 consecutive out columns
//     -> float4 epilogues, packed b64 LDS writes, 4 dR shuffles
//   - single 32KB buffer, non-persistent, 5 blocks/CU (v2-level gather
//     concurrency; v3's pipeline measured zero gain over this)
//   - weights per-tile from L2 (VGPR low -> occupancy)
// ---------------------------------------------------------------------------

#define F_IN   128
#define MID    192
#define OUT_N  128
#define K1     256          // 2*F (dR column handled as rank-1 epilogue)
#define M_TILE 64           // edges per block
#define H_STRIDE 200        // bf16 elements; 400 B rows

typedef __attribute__((ext_vector_type(8))) short bf16x8;            // 8 bf16 = 4 VGPRs
typedef __attribute__((ext_vector_type(8))) unsigned short u16x8;
typedef __attribute__((ext_vector_type(4))) float f32x4;
typedef __attribute__((ext_vector_type(2))) unsigned int u32x2;

__device__ __forceinline__ unsigned short f2bf(float f) {
    unsigned u = __builtin_bit_cast(unsigned, f);
    u = (u + 0x7FFFu + ((u >> 16) & 1u)) >> 16;   // round-to-nearest-even
    return (unsigned short)u;
}

// Pack W1 (rows 0..255) and W2 into bf16, fragment-major:
//   p[(ktile*N + n)*32 + kin], k = ktile*32 + kin.
// Used as the A-operand (W^T) fragment: lane(q,l15) reads 8 shorts at
// ((kt*N + nt*16+l15)*32 + q*8) = W[kt*32+q*8+j][nt*16+l15] = W^T[n][k].
__global__ void pack_weights(const float* __restrict__ W1,
                             const float* __restrict__ W2,
                             unsigned short* __restrict__ p1,
                             unsigned short* __restrict__ p2,
                             float* __restrict__ wdr) {
    int i = blockIdx.x * 256 + threadIdx.x;
    if (i < K1 * MID) {              // 49152
        int kin = i & 31;
        int rest = i >> 5;
        int n = rest % MID;
        int kt = rest / MID;
        p1[i] = f2bf(W1[(kt * 32 + kin) * MID + n]);
    }
    int j = i - K1 * MID;
    if (j >= 0 && j < MID * OUT_N) { // 24576
        int kin = j & 31;
        int rest = j >> 5;
        int n = rest & 127;
        int kt = rest >> 7;
        p2[j] = f2bf(W2[(kt * 32 + kin) * OUT_N + n]);
    }
    if (i < MID) wdr[i] = W1[256 * MID + i];
}

// h (fp32) -> hb (bf16), 8 elements/thread
__global__ void hconv(const float* __restrict__ h,
                      unsigned short* __restrict__ hb, int n8) {
    int i = blockIdx.x * 256 + threadIdx.x;
    if (i >= n8) return;
    const float4* hp = (const float4*)h;
    float4 v0 = hp[2 * i];
    float4 v1 = hp[2 * i + 1];
    u16x8 o;
    o[0] = f2bf(v0.x); o[1] = f2bf(v0.y); o[2] = f2bf(v0.z); o[3] = f2bf(v0.w);
    o[4] = f2bf(v1.x); o[5] = f2bf(v1.y); o[6] = f2bf(v1.z); o[7] = f2bf(v1.w);
    *((u16x8*)hb + i) = o;
}

__global__ __launch_bounds__(256, 5)
void edge_mlp_kernel(const unsigned short* __restrict__ hb,
                     const float* __restrict__ dR,
                     const int*   __restrict__ src_idx,
                     const int*   __restrict__ dst_idx,
                     const float* __restrict__ b1,
                     const float* __restrict__ b2,
                     const unsigned short* __restrict__ p1,
                     const unsigned short* __restrict__ p2,
                     const float* __restrict__ wdr,
                     float* __restrict__ out) {
    // A tile: 64 edges x 256 bf16 (dst row | src row), linear 512 B/edge.
    // 16B chunk c of edge e holds GLOBAL chunk c ^ (e&7) (source-side swizzle:
    // global_load_lds dest is wave-uniform base + lane*16, so LDS stays linear).
    __shared__ __align__(16) unsigned short sA[M_TILE * 256];   // 32768 B -> 5 blocks/CU

    const int tid  = threadIdx.x;
    const int lane = tid & 63;
    const int w    = tid >> 6;          // wave 0..3
    const int l15  = lane & 15;
    const int q    = lane >> 4;
    const int e0   = blockIdx.x * M_TILE;

    const float dr_own = dR[e0 + lane];

    // ---- stage A tile via global_load_lds (1 instr = 1024 B) ----
    {
        const int g = lane >> 4;        // {e dst, e src, e+1 dst, e+1 src}
        const int c = lane & 15;        // 16B chunk within a 256B row
        const int part = g & 1;
        const int* __restrict__ ip = part ? src_idx : dst_idx;
        const int eb = w * 16 + (g >> 1);
        int rows[8];
#pragma unroll
        for (int i = 0; i < 8; ++i) rows[i] = ip[e0 + eb + 2 * i];
#pragma unroll
        for (int i = 0; i < 8; ++i) {
            const int el = eb + 2 * i;
            const unsigned short* gp =
                hb + ((size_t)rows[i] << 7) + ((c ^ (el & 7)) << 3);
            unsigned short* lp = &sA[(w * 16 + 2 * i) * 256];   // wave-uniform
            __builtin_amdgcn_global_load_lds(
                (const __attribute__((address_space(1))) void*)gp,
                (__attribute__((address_space(3))) void*)lp, 16, 0, 0);
        }
    }
    __syncthreads();

    // ---- layer 1 (transposed): hid^T = W1^T (A) x A^T (B).
    //      acc1[mi][et]: C col = edge (l15), C row = n_local (q*4+r) ----
    f32x4 acc1[3][4] = {};
    for (int kt = 0; kt < 8; ++kt) {
        bf16x8 bfr[4];
#pragma unroll
        for (int et = 0; et < 4; ++et) {
            const int r = et * 16 + l15;
            bfr[et] = *(const bf16x8*)(&sA[r * 256 + (((kt * 4 + q) ^ (r & 7)) << 3)]);
        }
        bf16x8 w1a[3];
#pragma unroll
        for (int mi = 0; mi < 3; ++mi) {
            const int nb = (3 * w + mi) * 16 + l15;
            w1a[mi] = *(const bf16x8*)(&p1[((kt * MID + nb) << 5) + (q << 3)]);
        }
#pragma unroll
        for (int mi = 0; mi < 3; ++mi)
#pragma unroll
            for (int et = 0; et < 4; ++et)
                acc1[mi][et] = __builtin_amdgcn_mfma_f32_16x16x32_bf16(
                    w1a[mi], bfr[et], acc1[mi][et], 0, 0, 0);
    }
    __syncthreads();   // all waves done reading A before hid overwrites it

    // dR for the 4 edge columns this lane owns (e = et*16 + l15)
    float drl[4];
#pragma unroll
    for (int et = 0; et < 4; ++et) drl[et] = __shfl(dr_own, et * 16 + l15);

    // ---- epilogue 1 -> hid (bf16) in LDS [e][n], aliasing sA.
    //      lane holds n0..n0+3 consecutive for each (mi,et): packed b64 write ----
    unsigned short* sH = sA;
#pragma unroll
    for (int mi = 0; mi < 3; ++mi) {
        const int n0 = (3 * w + mi) * 16 + q * 4;
        const f32x4 bb = *(const f32x4*)(b1 + n0);
        const f32x4 wd = *(const f32x4*)(wdr + n0);
#pragma unroll
        for (int et = 0; et < 4; ++et) {
            const int e = et * 16 + l15;
            float v0 = fmaxf(acc1[mi][et][0] + bb[0] + drl[et] * wd[0], 0.0f);
            float v1 = fmaxf(acc1[mi][et][1] + bb[1] + drl[et] * wd[1], 0.0f);
            float v2 = fmaxf(acc1[mi][et][2] + bb[2] + drl[et] * wd[2], 0.0f);
            float v3 = fmaxf(acc1[mi][et][3] + bb[3] + drl[et] * wd[3], 0.0f);
            u32x2 pk;
            pk[0] = (unsigned)f2bf(v0) | ((unsigned)f2bf(v1) << 16);
            pk[1] = (unsigned)f2bf(v2) | ((unsigned)f2bf(v3) << 16);
            *(u32x2*)(&sH[e * H_STRIDE + n0]) = pk;
        }
    }
    __syncthreads();

    // ---- layer 2 (transposed): out^T = W2^T (A) x hid^T (B) ----
    f32x4 acc2[2][4] = {};
    for (int kt = 0; kt < 6; ++kt) {
        bf16x8 hfr[4];
#pragma unroll
        for (int et = 0; et < 4; ++et)
            hfr[et] = *(const bf16x8*)(&sH[(et * 16 + l15) * H_STRIDE + kt * 32 + q * 8]);
        bf16x8 w2a[2];
#pragma unroll
        for (int mi = 0; mi < 2; ++mi) {
            const int nb = (2 * w + mi) * 16 + l15;
            w2a[mi] = *(const bf16x8*)(&p2[((kt * OUT_N + nb) << 5) + (q << 3)]);
        }
#pragma unroll
        for (int mi = 0; mi < 2; ++mi)
#pragma unroll
            for (int et = 0; et < 4; ++et)
                acc2[mi][et] = __builtin_amdgcn_mfma_f32_16x16x32_bf16(
                    w2a[mi], hfr[et], acc2[mi][et], 0, 0, 0);
    }

    // ---- epilogue 2: tanh + PLAIN float4 stores (L2 write-allocate merges the
    //      wave's mi=0/1 64B halves into full 128B lines -> v1-verified 1.0x) ----
#pragma unroll
    for (int mi = 0; mi < 2; ++mi) {
        const int n0 = (2 * w + mi) * 16 + q * 4;
        const f32x4 bb2 = *(const f32x4*)(b2 + n0);
#pragma unroll
        for (int et = 0; et < 4; ++et) {
            const size_t e = (size_t)(e0 + et * 16 + l15);
            f32x4 y;
#pragma unroll
            for (int r = 0; r < 4; ++r) {
                float x = acc2[mi][et][r] + bb2[r];
                x = fminf(fmaxf(x, -10.0f), 10.0f);
                float tt = __expf(2.0f * x);              // tanh = (e^2x-1)/(e^2x+1)
                y[r] = (tt - 1.0f) * __builtin_amdgcn_rcpf(tt + 1.0f);
            }
            *(f32x4*)(out + e * OUT_N + n0) = y;
        }
    }
}

extern "C" void kernel_launch(void* const* d_in, const int* in_sizes, int n_in,
                              void* d_out, int out_size, void* d_ws, size_t ws_size,
                              hipStream_t stream) {
    const float* h   = (const float*)d_in[0];
    const float* dR  = (const float*)d_in[1];
    const int* src   = (const int*)d_in[2];
    const int* dst   = (const int*)d_in[3];
    const float* W1  = (const float*)d_in[4];
    const float* b1  = (const float*)d_in[5];
    const float* W2  = (const float*)d_in[6];
    const float* b2  = (const float*)d_in[7];
    float* out       = (float*)d_out;

    const int hn = in_sizes[0];   // n_nodes * 128 elements
    const int E  = in_sizes[1];

    // workspace layout: hb (hn bf16) | p1 | p2 | wdr   (~25.75 MB total)
    unsigned short* hbuf = (unsigned short*)d_ws;
    unsigned short* p1   = hbuf + hn;
    unsigned short* p2   = p1 + K1 * MID;
    float* wdr           = (float*)(p2 + MID * OUT_N);

    hconv<<<(hn / 8 + 255) / 256, 256, 0, stream>>>(h, hbuf, hn / 8);
    pack_weights<<<(K1 * MID + MID * OUT_N + 255) / 256, 256, 0, stream>>>(W1, W2, p1, p2, wdr);
    edge_mlp_kernel<<<E / M_TILE, 256, 0, stream>>>(hbuf, dR, src, dst, b1, b2, p1, p2, wdr, out);
}